// Round 2
// baseline (1714.160 us; speedup 1.0000x reference)
//
#include <hip/hip_runtime.h>
#include <hip/hip_bf16.h>

typedef __hip_bfloat16 bf16;
typedef __attribute__((ext_vector_type(8))) short bf16x8;
typedef __attribute__((ext_vector_type(4))) float f32x4;

#define NTOK   49
#define CDIM   256
#define NHEADS 8
#define HDIM   32
#define NWIN   64
#define BWIN   4096
#define MROWS  (BWIN * NTOK)      // 200704
#define QKVC   768
#define SCALE  0.17677669529663687f

__device__ __forceinline__ unsigned short f2bf(float f) {
    unsigned int u = __float_as_uint(f);
    u += 0x7fffu + ((u >> 16) & 1u);   // RNE
    return (unsigned short)(u >> 16);
}

__device__ __forceinline__ void load_lds16(const void* g, void* l) {
    __builtin_amdgcn_global_load_lds(
        (const __attribute__((address_space(1))) void*)g,
        (__attribute__((address_space(3))) void*)l, 16, 0, 0);
}

// ---------------------------------------------------------------------------
// Kernel 0: fp32 -> bf16 convert of x only (weights converted in-GEMM).
// ---------------------------------------------------------------------------
__global__ __launch_bounds__(256) void cvt_k(
    const float* __restrict__ x, bf16* __restrict__ xb)
{
    const long long NX = (long long)MROWS * CDIM / 4;
    const long long stride = (long long)gridDim.x * 256;
    for (long long i = (long long)blockIdx.x * 256 + threadIdx.x;
         i < NX; i += stride) {
        float4 v = ((const float4*)x)[i];
        ushort4 o;
        o.x = f2bf(v.x); o.y = f2bf(v.y); o.z = f2bf(v.z); o.w = f2bf(v.w);
        ((ushort4*)xb)[i] = o;
    }
}

// ---------------------------------------------------------------------------
// Kernel 1: qkv = x @ qkv_w^T + qkv_b via bf16 MFMA.
// 128x128 tile, BK=64, 4 waves (2x2), mfma_f32_16x16x32_bf16.
// A (bf16): global_load_lds(16B), linear LDS dest + pre-swizzled global src.
// B (fp32 weights): reg-staged (load float4 x2 -> cvt bf16 -> swizzled
// ds_write_b128). Swizzle: LDS slot s holds global slot s ^ (row&7).
// XCD-aware bijective block swizzle (nwg % 8 == 0).
// Output layout: [b][which(3)*8+h][n(49)][d(32)] bf16.
// ---------------------------------------------------------------------------
__global__ __launch_bounds__(256) void qkv_gemm_mfma(
    const bf16* __restrict__ A, const float* __restrict__ W,
    const float* __restrict__ bias, bf16* __restrict__ qkv)
{
    __shared__ bf16 As[128 * 64];
    __shared__ bf16 Bs[128 * 64];
    const int tid = threadIdx.x;
    const int wid = tid >> 6;
    const int ln  = tid & 63;

    // XCD swizzle: each XCD gets a contiguous chunk of tiles (col-fastest)
    const int lin   = blockIdx.y * gridDim.x + blockIdx.x;
    const int chunk = (gridDim.x * gridDim.y) >> 3;
    const int swz   = (lin & 7) * chunk + (lin >> 3);
    const int rowBase = (swz / gridDim.x) * 128;
    const int colBase = (swz % gridDim.x) * 128;

    const int wr = wid >> 1, wc = wid & 1;   // 2x2 wave grid, 64x64 per wave

    f32x4 zero = {0.f, 0.f, 0.f, 0.f};
    f32x4 acc[4][4];
#pragma unroll
    for (int i = 0; i < 4; ++i)
#pragma unroll
        for (int j = 0; j < 4; ++j) acc[i][j] = zero;

    const int srow  = ln >> 3;                 // row within 8-row chunk (0..7)
    const int gslot = ln & 7;                  // this lane's 16B slot index
    const int sslotA = gslot ^ srow;           // pre-swizzled A global slot
    const int swslotB = gslot ^ srow;          // swizzled B LDS slot
    const size_t aRow0 = (size_t)(rowBase + wid * 32);
    const size_t bRow0 = (size_t)(colBase + wid * 32);

    for (int k0 = 0; k0 < CDIM; k0 += 64) {
        // ---- A: async direct-to-LDS (linear dest; source pre-swizzled) ----
#pragma unroll
        for (int c = 0; c < 4; ++c) {
            const bf16* ga = A + (aRow0 + c * 8 + srow) * CDIM + k0 + sslotA * 8;
            load_lds16(ga, &As[(wid * 32 + c * 8) * 64]);
        }
        // ---- B: reg-stage fp32 weights -> bf16 -> swizzled LDS write ----
        float4 f0[4], f1[4];
#pragma unroll
        for (int c = 0; c < 4; ++c) {
            const float* gw = W + (size_t)(bRow0 + c * 8 + srow) * CDIM
                              + k0 + gslot * 8;
            f0[c] = *(const float4*)gw;
            f1[c] = *(const float4*)(gw + 4);
        }
#pragma unroll
        for (int c = 0; c < 4; ++c) {
            bf16x8 pk;
            pk[0] = (short)f2bf(f0[c].x); pk[1] = (short)f2bf(f0[c].y);
            pk[2] = (short)f2bf(f0[c].z); pk[3] = (short)f2bf(f0[c].w);
            pk[4] = (short)f2bf(f1[c].x); pk[5] = (short)f2bf(f1[c].y);
            pk[6] = (short)f2bf(f1[c].z); pk[7] = (short)f2bf(f1[c].w);
            *(bf16x8*)((char*)Bs + (wid * 32 + c * 8 + srow) * 128
                       + (swslotB << 4)) = pk;
        }
        __syncthreads();
#pragma unroll
        for (int kk = 0; kk < 2; ++kk) {
            bf16x8 av[4], bv[4];
#pragma unroll
            for (int m = 0; m < 4; ++m) {
                int r = wr * 64 + m * 16 + (ln & 15);
                int g = kk * 4 + (ln >> 4);
                av[m] = *(const bf16x8*)((const char*)As +
                          (r * 128 + ((g ^ (r & 7)) << 4)));
            }
#pragma unroll
            for (int n = 0; n < 4; ++n) {
                int r = wc * 64 + n * 16 + (ln & 15);
                int g = kk * 4 + (ln >> 4);
                bv[n] = *(const bf16x8*)((const char*)Bs +
                          (r * 128 + ((g ^ (r & 7)) << 4)));
            }
#pragma unroll
            for (int m = 0; m < 4; ++m)
#pragma unroll
                for (int n = 0; n < 4; ++n)
                    acc[m][n] = __builtin_amdgcn_mfma_f32_16x16x32_bf16(
                        av[m], bv[n], acc[m][n], 0, 0, 0);
        }
        __syncthreads();
    }

    // Epilogue: C/D layout col=lane&15, row=(lane>>4)*4+q (guide §3, m89)
    const int lq = ln >> 4;
    const int lr = ln & 15;
#pragma unroll
    for (int m = 0; m < 4; ++m) {
#pragma unroll
        for (int q = 0; q < 4; ++q) {
            int row = rowBase + wr * 64 + m * 16 + lq * 4 + q;
            int bw = row / NTOK;
            int nn = row - bw * NTOK;
            bf16* dst0 = qkv + (size_t)bw * 24 * (NTOK * HDIM) + nn * HDIM;
#pragma unroll
            for (int n = 0; n < 4; ++n) {
                int col = colBase + wc * 64 + n * 16 + lr;
                int which = col >> 8, hh = (col >> 5) & 7, dd = col & 31;
                float v = acc[m][n][q] + bias[col];
                dst0[(size_t)(which * 8 + hh) * (NTOK * HDIM) + dd] =
                    __float2bfloat16(v);
            }
        }
    }
}

// ---------------------------------------------------------------------------
// Kernel 2: per (window b, head h): S = q k^T * scale + bias + mask,
//           P = softmax(S) -> attn out; O = P v -> ws (bf16) [UNCHANGED]
// ---------------------------------------------------------------------------
__global__ __launch_bounds__(256) void attn_k(
    const bf16* __restrict__ qkv, const float* __restrict__ mask,
    const float* __restrict__ bt, float* __restrict__ attn_out,
    bf16* __restrict__ o_ws)
{
    const int b = blockIdx.x;
    const int h = blockIdx.y;
    const int tid = threadIdx.x;
    const int wv = tid >> 6, ln = tid & 63;

    __shared__ float qs[NTOK * 33];
    __shared__ float ks[NTOK * 33];
    __shared__ float vs[NTOK * 33];
    __shared__ float ps[NTOK * 50];

    const bf16* qp = qkv + (size_t)(b*24 + h)      * (NTOK*HDIM);
    const bf16* kp = qkv + (size_t)(b*24 + 8 + h)  * (NTOK*HDIM);
    const bf16* vp = qkv + (size_t)(b*24 + 16 + h) * (NTOK*HDIM);

    for (int e = tid; e < NTOK*HDIM; e += 256) {
        int n = e >> 5, d = e & 31;
        qs[n*33+d] = (float)qp[e];
        ks[n*33+d] = (float)kp[e];
        vs[n*33+d] = (float)vp[e];
    }
    __syncthreads();

    const float* mrow = mask + (size_t)(b & (NWIN-1)) * (NTOK*NTOK);
    float* aout = attn_out + (((size_t)b * NHEADS + h) * NTOK) * NTOK;

    for (int i = wv; i < NTOK; i += 4) {
        float s = -1e30f;
        if (ln < NTOK) {
            int j = ln;
            float acc = 0.f;
#pragma unroll
            for (int d = 0; d < HDIM; ++d) acc += qs[i*33+d] * ks[j*33+d];
            int ih = i / 7, iw = i - ih*7;
            int jh = j / 7, jw = j - jh*7;
            float bias = bt[((ih - jh + 6)*13 + (iw - jw + 6)) * NHEADS + h];
            s = acc * SCALE + bias + mrow[i*NTOK + j];
        }
        float mx = s;
#pragma unroll
        for (int off = 32; off; off >>= 1) mx = fmaxf(mx, __shfl_xor(mx, off));
        float ev = (ln < NTOK) ? __expf(s - mx) : 0.f;
        float sum = ev;
#pragma unroll
        for (int off = 32; off; off >>= 1) sum += __shfl_xor(sum, off);
        float p = ev / sum;
        if (ln < NTOK) {
            ps[i*50 + ln] = p;
            aout[(size_t)i * NTOK + ln] = p;
        }
    }
    __syncthreads();

    for (int i0 = wv*2; i0 < NTOK; i0 += 8) {
        int i = i0 + (ln >> 5);
        int d = ln & 31;
        if (i < NTOK) {
            float acc = 0.f;
            for (int j = 0; j < NTOK; ++j) acc += ps[i*50+j] * vs[j*33+d];
            o_ws[((size_t)b*NTOK + i) * CDIM + h*HDIM + d] = __float2bfloat16(acc);
        }
    }
}

// ---------------------------------------------------------------------------
// Kernel 3: out = O @ proj_w^T + proj_b via bf16 MFMA (same core as kernel 1)
// ---------------------------------------------------------------------------
__global__ __launch_bounds__(256) void proj_gemm_mfma(
    const bf16* __restrict__ A, const float* __restrict__ W,
    const float* __restrict__ bias, float* __restrict__ out)
{
    __shared__ bf16 As[128 * 64];
    __shared__ bf16 Bs[128 * 64];
    const int tid = threadIdx.x;
    const int wid = tid >> 6;
    const int ln  = tid & 63;

    const int lin   = blockIdx.y * gridDim.x + blockIdx.x;
    const int chunk = (gridDim.x * gridDim.y) >> 3;
    const int swz   = (lin & 7) * chunk + (lin >> 3);
    const int rowBase = (swz / gridDim.x) * 128;
    const int colBase = (swz % gridDim.x) * 128;

    const int wr = wid >> 1, wc = wid & 1;

    f32x4 zero = {0.f, 0.f, 0.f, 0.f};
    f32x4 acc[4][4];
#pragma unroll
    for (int i = 0; i < 4; ++i)
#pragma unroll
        for (int j = 0; j < 4; ++j) acc[i][j] = zero;

    const int srow  = ln >> 3;
    const int gslot = ln & 7;
    const int sslotA = gslot ^ srow;
    const int swslotB = gslot ^ srow;
    const size_t aRow0 = (size_t)(rowBase + wid * 32);
    const size_t bRow0 = (size_t)(colBase + wid * 32);

    for (int k0 = 0; k0 < CDIM; k0 += 64) {
#pragma unroll
        for (int c = 0; c < 4; ++c) {
            const bf16* ga = A + (aRow0 + c * 8 + srow) * CDIM + k0 + sslotA * 8;
            load_lds16(ga, &As[(wid * 32 + c * 8) * 64]);
        }
        float4 f0[4], f1[4];
#pragma unroll
        for (int c = 0; c < 4; ++c) {
            const float* gw = W + (size_t)(bRow0 + c * 8 + srow) * CDIM
                              + k0 + gslot * 8;
            f0[c] = *(const float4*)gw;
            f1[c] = *(const float4*)(gw + 4);
        }
#pragma unroll
        for (int c = 0; c < 4; ++c) {
            bf16x8 pk;
            pk[0] = (short)f2bf(f0[c].x); pk[1] = (short)f2bf(f0[c].y);
            pk[2] = (short)f2bf(f0[c].z); pk[3] = (short)f2bf(f0[c].w);
            pk[4] = (short)f2bf(f1[c].x); pk[5] = (short)f2bf(f1[c].y);
            pk[6] = (short)f2bf(f1[c].z); pk[7] = (short)f2bf(f1[c].w);
            *(bf16x8*)((char*)Bs + (wid * 32 + c * 8 + srow) * 128
                       + (swslotB << 4)) = pk;
        }
        __syncthreads();
#pragma unroll
        for (int kk = 0; kk < 2; ++kk) {
            bf16x8 av[4], bv[4];
#pragma unroll
            for (int m = 0; m < 4; ++m) {
                int r = wr * 64 + m * 16 + (ln & 15);
                int g = kk * 4 + (ln >> 4);
                av[m] = *(const bf16x8*)((const char*)As +
                          (r * 128 + ((g ^ (r & 7)) << 4)));
            }
#pragma unroll
            for (int n = 0; n < 4; ++n) {
                int r = wc * 64 + n * 16 + (ln & 15);
                int g = kk * 4 + (ln >> 4);
                bv[n] = *(const bf16x8*)((const char*)Bs +
                          (r * 128 + ((g ^ (r & 7)) << 4)));
            }
#pragma unroll
            for (int m = 0; m < 4; ++m)
#pragma unroll
                for (int n = 0; n < 4; ++n)
                    acc[m][n] = __builtin_amdgcn_mfma_f32_16x16x32_bf16(
                        av[m], bv[n], acc[m][n], 0, 0, 0);
        }
        __syncthreads();
    }

    const int lq = ln >> 4;
    const int lr = ln & 15;
#pragma unroll
    for (int m = 0; m < 4; ++m) {
#pragma unroll
        for (int q = 0; q < 4; ++q) {
            int row = rowBase + wr * 64 + m * 16 + lq * 4 + q;
            float* orow = out + (size_t)row * CDIM;
#pragma unroll
            for (int n = 0; n < 4; ++n) {
                int col = colBase + wc * 64 + n * 16 + lr;
                orow[col] = acc[m][n][q] + bias[col];
            }
        }
    }
}

// ---------------------------------------------------------------------------
extern "C" void kernel_launch(void* const* d_in, const int* in_sizes, int n_in,
                              void* d_out, int out_size, void* d_ws, size_t ws_size,
                              hipStream_t stream)
{
    const float* x      = (const float*)d_in[0];   // [4096,49,256]
    const float* mask   = (const float*)d_in[1];   // [64,49,49]
    const float* qkv_w  = (const float*)d_in[2];   // [768,256]
    const float* qkv_b  = (const float*)d_in[3];   // [768]
    const float* proj_w = (const float*)d_in[4];   // [256,256]
    const float* proj_b = (const float*)d_in[5];   // [256]
    const float* bt     = (const float*)d_in[6];   // [169,8]

    float* out      = (float*)d_out;                       // [4096,49,256]
    float* attn_out = out + (size_t)MROWS * CDIM;          // [4096,8,49,49]

    bf16* qkv_ws = (bf16*)d_ws;                            // [MROWS*768] bf16
    bf16* xo_ws  = qkv_ws + (size_t)MROWS * QKVC;          // x_bf16, later o_ws
    // total ws footprint: MROWS*(768+256)*2 B = 411,041,792 B (== prior kernel)

    // Kernel 0: x fp32 -> bf16 into xo_ws
    cvt_k<<<2048, 256, 0, stream>>>(x, xo_ws);

    // Kernel 1: QKV projection via MFMA. grid (768/128, 200704/128)
    qkv_gemm_mfma<<<dim3(QKVC/128, MROWS/128), 256, 0, stream>>>(
        xo_ws, qkv_w, qkv_b, qkv_ws);

    // Kernel 2: attention per (window, head); writes O into xo_ws (x_bf16 dead)
    attn_k<<<dim3(BWIN, NHEADS), 256, 0, stream>>>(qkv_ws, mask, bt, attn_out, xo_ws);

    // Kernel 3: output projection via MFMA. grid (256/128, 200704/128)
    proj_gemm_mfma<<<dim3(CDIM/128, MROWS/128), 256, 0, stream>>>(
        xo_ws, proj_w, proj_b, out);
}

// Round 5
// 1145.520 us; speedup vs baseline: 1.4964x; 1.4964x over previous
//
#include <hip/hip_runtime.h>
#include <hip/hip_bf16.h>

typedef __hip_bfloat16 bf16;
typedef __attribute__((ext_vector_type(8))) short bf16x8;
typedef __attribute__((ext_vector_type(4))) float f32x4;

#define NTOK   49
#define CDIM   256
#define NHEADS 8
#define HDIM   32
#define NWIN   64
#define BWIN   4096
#define MROWS  (BWIN * NTOK)      // 200704
#define QKVC   768
#define SCALE  0.17677669529663687f

__device__ __forceinline__ unsigned short f2bf(float f) {
    unsigned int u = __float_as_uint(f);
    u += 0x7fffu + ((u >> 16) & 1u);   // RNE
    return (unsigned short)(u >> 16);
}

__device__ __forceinline__ void load_lds16(const void* g, void* l) {
    __builtin_amdgcn_global_load_lds(
        (const __attribute__((address_space(1))) void*)g,
        (__attribute__((address_space(3))) void*)l, 16, 0, 0);
}

// ---------------------------------------------------------------------------
// Kernel 0: fp32 -> bf16 convert of x only (weights converted in-GEMM).
// ---------------------------------------------------------------------------
__global__ __launch_bounds__(256) void cvt_k(
    const float* __restrict__ x, bf16* __restrict__ xb)
{
    const long long NX = (long long)MROWS * CDIM / 4;
    const long long stride = (long long)gridDim.x * 256;
    for (long long i = (long long)blockIdx.x * 256 + threadIdx.x;
         i < NX; i += stride) {
        float4 v = ((const float4*)x)[i];
        ushort4 o;
        o.x = f2bf(v.x); o.y = f2bf(v.y); o.z = f2bf(v.z); o.w = f2bf(v.w);
        ((ushort4*)xb)[i] = o;
    }
}

// ---------------------------------------------------------------------------
// Kernel 1: qkv = x @ qkv_w^T + qkv_b via bf16 MFMA.  [verified passing R2]
// ---------------------------------------------------------------------------
__global__ __launch_bounds__(256) void qkv_gemm_mfma(
    const bf16* __restrict__ A, const float* __restrict__ W,
    const float* __restrict__ bias, bf16* __restrict__ qkv)
{
    __shared__ bf16 As[128 * 64];
    __shared__ bf16 Bs[128 * 64];
    const int tid = threadIdx.x;
    const int wid = tid >> 6;
    const int ln  = tid & 63;

    const int lin   = blockIdx.y * gridDim.x + blockIdx.x;
    const int chunk = (gridDim.x * gridDim.y) >> 3;
    const int swz   = (lin & 7) * chunk + (lin >> 3);
    const int rowBase = (swz / gridDim.x) * 128;
    const int colBase = (swz % gridDim.x) * 128;

    const int wr = wid >> 1, wc = wid & 1;

    f32x4 zero = {0.f, 0.f, 0.f, 0.f};
    f32x4 acc[4][4];
#pragma unroll
    for (int i = 0; i < 4; ++i)
#pragma unroll
        for (int j = 0; j < 4; ++j) acc[i][j] = zero;

    const int srow  = ln >> 3;
    const int gslot = ln & 7;
    const int sslotA = gslot ^ srow;
    const int swslotB = gslot ^ srow;
    const size_t aRow0 = (size_t)(rowBase + wid * 32);
    const size_t bRow0 = (size_t)(colBase + wid * 32);

    for (int k0 = 0; k0 < CDIM; k0 += 64) {
#pragma unroll
        for (int c = 0; c < 4; ++c) {
            const bf16* ga = A + (aRow0 + c * 8 + srow) * CDIM + k0 + sslotA * 8;
            load_lds16(ga, &As[(wid * 32 + c * 8) * 64]);
        }
        float4 f0[4], f1[4];
#pragma unroll
        for (int c = 0; c < 4; ++c) {
            const float* gw = W + (size_t)(bRow0 + c * 8 + srow) * CDIM
                              + k0 + gslot * 8;
            f0[c] = *(const float4*)gw;
            f1[c] = *(const float4*)(gw + 4);
        }
#pragma unroll
        for (int c = 0; c < 4; ++c) {
            bf16x8 pk;
            pk[0] = (short)f2bf(f0[c].x); pk[1] = (short)f2bf(f0[c].y);
            pk[2] = (short)f2bf(f0[c].z); pk[3] = (short)f2bf(f0[c].w);
            pk[4] = (short)f2bf(f1[c].x); pk[5] = (short)f2bf(f1[c].y);
            pk[6] = (short)f2bf(f1[c].z); pk[7] = (short)f2bf(f1[c].w);
            *(bf16x8*)((char*)Bs + (wid * 32 + c * 8 + srow) * 128
                       + (swslotB << 4)) = pk;
        }
        __syncthreads();
#pragma unroll
        for (int kk = 0; kk < 2; ++kk) {
            bf16x8 av[4], bv[4];
#pragma unroll
            for (int m = 0; m < 4; ++m) {
                int r = wr * 64 + m * 16 + (ln & 15);
                int g = kk * 4 + (ln >> 4);
                av[m] = *(const bf16x8*)((const char*)As +
                          (r * 128 + ((g ^ (r & 7)) << 4)));
            }
#pragma unroll
            for (int n = 0; n < 4; ++n) {
                int r = wc * 64 + n * 16 + (ln & 15);
                int g = kk * 4 + (ln >> 4);
                bv[n] = *(const bf16x8*)((const char*)Bs +
                          (r * 128 + ((g ^ (r & 7)) << 4)));
            }
#pragma unroll
            for (int m = 0; m < 4; ++m)
#pragma unroll
                for (int n = 0; n < 4; ++n)
                    acc[m][n] = __builtin_amdgcn_mfma_f32_16x16x32_bf16(
                        av[m], bv[n], acc[m][n], 0, 0, 0);
        }
        __syncthreads();
    }

    const int lq = ln >> 4;
    const int lr = ln & 15;
#pragma unroll
    for (int m = 0; m < 4; ++m) {
#pragma unroll
        for (int q = 0; q < 4; ++q) {
            int row = rowBase + wr * 64 + m * 16 + lq * 4 + q;
            int bw = row / NTOK;
            int nn = row - bw * NTOK;
            bf16* dst0 = qkv + (size_t)bw * 24 * (NTOK * HDIM) + nn * HDIM;
#pragma unroll
            for (int n = 0; n < 4; ++n) {
                int col = colBase + wc * 64 + n * 16 + lr;
                int which = col >> 8, hh = (col >> 5) & 7, dd = col & 31;
                float v = acc[m][n][q] + bias[col];
                dst0[(size_t)(which * 8 + hh) * (NTOK * HDIM) + dd] =
                    __float2bfloat16(v);
            }
        }
    }
}

// ---------------------------------------------------------------------------
// Kernel 2: MFMA attention. One block per window b; wave w handles heads
// w and w+4. Q/K fragments direct from global; S^T = mfma(K,Q); fp32
// softmax in-register; attn_out fp32 from regs; P bf16 -> wave-private
// swizzled LDS; V transposed -> wave-private swizzled LDS; O = mfma(P,V).
// No __syncthreads (all LDS wave-private).
// ---------------------------------------------------------------------------
__global__ __launch_bounds__(256) void attn_mfma_k(
    const bf16* __restrict__ qkv, const float* __restrict__ mask,
    const float* __restrict__ bt, float* __restrict__ attn_out,
    bf16* __restrict__ o_ws)
{
    const int b  = blockIdx.x;
    const int wv = threadIdx.x >> 6;
    const int ln = threadIdx.x & 63;
    const int r  = ln & 15;     // fragment row/col lane
    const int g  = ln >> 4;     // k-group 0..3

    __shared__ short vt_all[4][32 * 64];   // Vt[d][j], swizzled, 4KB/wave
    __shared__ short ps_all[4][64 * 64];   // P[i][j],  swizzled, 8KB/wave
    char* vt = (char*)vt_all[wv];
    char* ps = (char*)ps_all[wv];

    const float* mrow = mask + (size_t)(b & (NWIN - 1)) * (NTOK * NTOK);

#pragma unroll 1
    for (int hh = 0; hh < 2; ++hh) {
        const int h = wv + hh * 4;
        const bf16* qp = qkv + ((size_t)b * 24 + h)      * (NTOK * HDIM);
        const bf16* kp = qkv + ((size_t)b * 24 + 8 + h)  * (NTOK * HDIM);
        const bf16* vp = qkv + ((size_t)b * 24 + 16 + h) * (NTOK * HDIM);

        // ---- Q,K fragments direct from global (rows clamped to 48) ----
        bf16x8 qf[4], kf[4];
#pragma unroll
        for (int t = 0; t < 4; ++t) {
            int qi = t * 16 + r; if (qi > 48) qi = 48;
            qf[t] = *(const bf16x8*)(qp + qi * HDIM + g * 8);
            kf[t] = *(const bf16x8*)(kp + qi * HDIM + g * 8);
        }

        // ---- stage V transposed into LDS: Vt[d][j=ln], zero pad j>=49 ----
        bf16x8 vr0 = {0,0,0,0,0,0,0,0}, vr1 = vr0, vr2 = vr0, vr3 = vr0;
        if (ln < NTOK) {
            vr0 = *(const bf16x8*)(vp + ln * HDIM);
            vr1 = *(const bf16x8*)(vp + ln * HDIM + 8);
            vr2 = *(const bf16x8*)(vp + ln * HDIM + 16);
            vr3 = *(const bf16x8*)(vp + ln * HDIM + 24);
        }
#pragma unroll
        for (int d = 0; d < 32; ++d) {
            short val = (d < 8) ? vr0[d & 7] : (d < 16) ? vr1[d & 7]
                      : (d < 24) ? vr2[d & 7] : vr3[d & 7];
            *(short*)(vt + d * 128 + ((((ln >> 3)) ^ (d & 7)) << 4)
                      + (ln & 7) * 2) = val;
        }

        // ---- QK^T: S^T tile; s[mt][nt], m=j (K rows), n=i (Q rows) ----
        f32x4 zero = {0.f, 0.f, 0.f, 0.f};
        f32x4 s[4][4];
#pragma unroll
        for (int mt = 0; mt < 4; ++mt)
#pragma unroll
            for (int nt = 0; nt < 4; ++nt) s[mt][nt] = zero;
#pragma unroll
        for (int mt = 0; mt < 4; ++mt)
#pragma unroll
            for (int nt = 0; nt < 4; ++nt)
                s[mt][nt] = __builtin_amdgcn_mfma_f32_16x16x32_bf16(
                    kf[mt], qf[nt], s[mt][nt], 0, 0, 0);

        // ---- bias + mask + softmax (per nt: row i = nt*16+r) ----
        float* aout = attn_out + (((size_t)b * NHEADS + h) * NTOK) * NTOK;
#pragma unroll
        for (int nt = 0; nt < 4; ++nt) {
            const int i = nt * 16 + r;
            const bool iok = (i < NTOK);
            const int ih = (i * 9363) >> 16;
            const int iw = i - ih * 7;
            float sv[4][4];
#pragma unroll
            for (int mt = 0; mt < 4; ++mt)
#pragma unroll
                for (int q = 0; q < 4; ++q) {
                    const int j = mt * 16 + g * 4 + q;
                    float v = -1e30f;
                    if (iok && j < NTOK) {
                        const int jh = (j * 9363) >> 16;
                        const int jw = j - jh * 7;
                        float bias = bt[((ih - jh + 6) * 13 +
                                         (iw - jw + 6)) * NHEADS + h];
                        v = s[mt][nt][q] * SCALE + bias + mrow[i * NTOK + j];
                    }
                    sv[mt][q] = v;
                }
            float mx = -1e30f;
#pragma unroll
            for (int mt = 0; mt < 4; ++mt)
#pragma unroll
                for (int q = 0; q < 4; ++q) mx = fmaxf(mx, sv[mt][q]);
            mx = fmaxf(mx, __shfl_xor(mx, 16));
            mx = fmaxf(mx, __shfl_xor(mx, 32));
            float sum = 0.f;
#pragma unroll
            for (int mt = 0; mt < 4; ++mt)
#pragma unroll
                for (int q = 0; q < 4; ++q) {
                    sv[mt][q] = __expf(sv[mt][q] - mx);
                    sum += sv[mt][q];
                }
            sum += __shfl_xor(sum, 16);
            sum += __shfl_xor(sum, 32);
            const float inv = 1.0f / sum;
            // write attn_out (fp32) + pack P bf16 into swizzled LDS
#pragma unroll
            for (int mt = 0; mt < 4; ++mt) {
#pragma unroll
                for (int qh = 0; qh < 2; ++qh) {
                    float p0 = sv[mt][qh * 2]     * inv;
                    float p1 = sv[mt][qh * 2 + 1] * inv;
                    const int j0 = mt * 16 + g * 4 + qh * 2;
                    if (iok) {
                        if (j0 < NTOK)     aout[(size_t)i * NTOK + j0]     = p0;
                        if (j0 + 1 < NTOK) aout[(size_t)i * NTOK + j0 + 1] = p1;
                    }
                    unsigned int pk = (unsigned int)f2bf(p0) |
                                      ((unsigned int)f2bf(p1) << 16);
                    *(unsigned int*)(ps + i * 128 +
                        (((2 * mt + (g >> 1)) ^ (r & 7)) << 4) +
                        (g & 1) * 8 + qh * 4) = pk;
                }
            }
        }

        // ---- PV: O[i][d] = sum_j P[i][j] V[j][d] ----
        f32x4 o[4][2];
#pragma unroll
        for (int mt = 0; mt < 4; ++mt)
#pragma unroll
            for (int nt = 0; nt < 2; ++nt) o[mt][nt] = zero;
#pragma unroll
        for (int ks = 0; ks < 2; ++ks) {
            bf16x8 pa[4], vb[2];
#pragma unroll
            for (int mt = 0; mt < 4; ++mt) {
                const int row = mt * 16 + r;
                pa[mt] = *(const bf16x8*)(ps + row * 128 +
                           (((ks * 4 + g) ^ (r & 7)) << 4));
            }
#pragma unroll
            for (int nt = 0; nt < 2; ++nt) {
                const int row = nt * 16 + r;
                vb[nt] = *(const bf16x8*)(vt + row * 128 +
                           (((ks * 4 + g) ^ (r & 7)) << 4));
            }
#pragma unroll
            for (int mt = 0; mt < 4; ++mt)
#pragma unroll
                for (int nt = 0; nt < 2; ++nt)
                    o[mt][nt] = __builtin_amdgcn_mfma_f32_16x16x32_bf16(
                        pa[mt], vb[nt], o[mt][nt], 0, 0, 0);
        }

        // ---- store O (bf16) into o_ws[b][i][h*32+d] ----
#pragma unroll
        for (int mt = 0; mt < 4; ++mt) {
#pragma unroll
            for (int q = 0; q < 4; ++q) {
                const int i = mt * 16 + g * 4 + q;
                if (i < NTOK) {
#pragma unroll
                    for (int nt = 0; nt < 2; ++nt) {
                        const int d = nt * 16 + r;
                        o_ws[((size_t)b * NTOK + i) * CDIM + h * HDIM + d] =
                            __float2bfloat16(o[mt][nt][q]);
                    }
                }
            }
        }
    }
}

// ---------------------------------------------------------------------------
// Kernel 3: out = O @ proj_w^T + proj_b via bf16 MFMA.  [verified passing R2]
// ---------------------------------------------------------------------------
__global__ __launch_bounds__(256) void proj_gemm_mfma(
    const bf16* __restrict__ A, const float* __restrict__ W,
    const float* __restrict__ bias, float* __restrict__ out)
{
    __shared__ bf16 As[128 * 64];
    __shared__ bf16 Bs[128 * 64];
    const int tid = threadIdx.x;
    const int wid = tid >> 6;
    const int ln  = tid & 63;

    const int lin   = blockIdx.y * gridDim.x + blockIdx.x;
    const int chunk = (gridDim.x * gridDim.y) >> 3;
    const int swz   = (lin & 7) * chunk + (lin >> 3);
    const int rowBase = (swz / gridDim.x) * 128;
    const int colBase = (swz % gridDim.x) * 128;

    const int wr = wid >> 1, wc = wid & 1;

    f32x4 zero = {0.f, 0.f, 0.f, 0.f};
    f32x4 acc[4][4];
#pragma unroll
    for (int i = 0; i < 4; ++i)
#pragma unroll
        for (int j = 0; j < 4; ++j) acc[i][j] = zero;

    const int srow  = ln >> 3;
    const int gslot = ln & 7;
    const int sslotA = gslot ^ srow;
    const int swslotB = gslot ^ srow;
    const size_t aRow0 = (size_t)(rowBase + wid * 32);
    const size_t bRow0 = (size_t)(colBase + wid * 32);

    for (int k0 = 0; k0 < CDIM; k0 += 64) {
#pragma unroll
        for (int c = 0; c < 4; ++c) {
            const bf16* ga = A + (aRow0 + c * 8 + srow) * CDIM + k0 + sslotA * 8;
            load_lds16(ga, &As[(wid * 32 + c * 8) * 64]);
        }
        float4 f0[4], f1[4];
#pragma unroll
        for (int c = 0; c < 4; ++c) {
            const float* gw = W + (size_t)(bRow0 + c * 8 + srow) * CDIM
                              + k0 + gslot * 8;
            f0[c] = *(const float4*)gw;
            f1[c] = *(const float4*)(gw + 4);
        }
#pragma unroll
        for (int c = 0; c < 4; ++c) {
            bf16x8 pk;
            pk[0] = (short)f2bf(f0[c].x); pk[1] = (short)f2bf(f0[c].y);
            pk[2] = (short)f2bf(f0[c].z); pk[3] = (short)f2bf(f0[c].w);
            pk[4] = (short)f2bf(f1[c].x); pk[5] = (short)f2bf(f1[c].y);
            pk[6] = (short)f2bf(f1[c].z); pk[7] = (short)f2bf(f1[c].w);
            *(bf16x8*)((char*)Bs + (wid * 32 + c * 8 + srow) * 128
                       + (swslotB << 4)) = pk;
        }
        __syncthreads();
#pragma unroll
        for (int kk = 0; kk < 2; ++kk) {
            bf16x8 av[4], bv[4];
#pragma unroll
            for (int m = 0; m < 4; ++m) {
                int r = wr * 64 + m * 16 + (ln & 15);
                int g = kk * 4 + (ln >> 4);
                av[m] = *(const bf16x8*)((const char*)As +
                          (r * 128 + ((g ^ (r & 7)) << 4)));
            }
#pragma unroll
            for (int n = 0; n < 4; ++n) {
                int r = wc * 64 + n * 16 + (ln & 15);
                int g = kk * 4 + (ln >> 4);
                bv[n] = *(const bf16x8*)((const char*)Bs +
                          (r * 128 + ((g ^ (r & 7)) << 4)));
            }
#pragma unroll
            for (int m = 0; m < 4; ++m)
#pragma unroll
                for (int n = 0; n < 4; ++n)
                    acc[m][n] = __builtin_amdgcn_mfma_f32_16x16x32_bf16(
                        av[m], bv[n], acc[m][n], 0, 0, 0);
        }
        __syncthreads();
    }

    const int lq = ln >> 4;
    const int lr = ln & 15;
#pragma unroll
    for (int m = 0; m < 4; ++m) {
#pragma unroll
        for (int q = 0; q < 4; ++q) {
            int row = rowBase + wr * 64 + m * 16 + lq * 4 + q;
            float* orow = out + (size_t)row * CDIM;
#pragma unroll
            for (int n = 0; n < 4; ++n) {
                int col = colBase + wc * 64 + n * 16 + lr;
                orow[col] = acc[m][n][q] + bias[col];
            }
        }
    }
}

// ---------------------------------------------------------------------------
extern "C" void kernel_launch(void* const* d_in, const int* in_sizes, int n_in,
                              void* d_out, int out_size, void* d_ws, size_t ws_size,
                              hipStream_t stream)
{
    const float* x      = (const float*)d_in[0];   // [4096,49,256]
    const float* mask   = (const float*)d_in[1];   // [64,49,49]
    const float* qkv_w  = (const float*)d_in[2];   // [768,256]
    const float* qkv_b  = (const float*)d_in[3];   // [768]
    const float* proj_w = (const float*)d_in[4];   // [256,256]
    const float* proj_b = (const float*)d_in[5];   // [256]
    const float* bt     = (const float*)d_in[6];   // [169,8]

    float* out      = (float*)d_out;                       // [4096,49,256]
    float* attn_out = out + (size_t)MROWS * CDIM;          // [4096,8,49,49]

    bf16* qkv_ws = (bf16*)d_ws;                            // [MROWS*768] bf16
    bf16* xo_ws  = qkv_ws + (size_t)MROWS * QKVC;          // x_bf16, later o_ws
    // total ws footprint: MROWS*(768+256)*2 B = 411,041,792 B

    cvt_k<<<2048, 256, 0, stream>>>(x, xo_ws);

    qkv_gemm_mfma<<<dim3(QKVC/128, MROWS/128), 256, 0, stream>>>(
        xo_ws, qkv_w, qkv_b, qkv_ws);

    attn_mfma_k<<<dim3(BWIN), 256, 0, stream>>>(qkv_ws, mask, bt,
                                                attn_out, xo_ws);

    proj_gemm_mfma<<<dim3(CDIM/128, MROWS/128), 256, 0, stream>>>(
        xo_ws, proj_w, proj_b, out);
}

// Round 7
// 1129.099 us; speedup vs baseline: 1.5182x; 1.0145x over previous
//
#include <hip/hip_runtime.h>
#include <hip/hip_bf16.h>

typedef __hip_bfloat16 bf16;
typedef __attribute__((ext_vector_type(8))) short bf16x8;
typedef __attribute__((ext_vector_type(4))) float f32x4;

#define NTOK   49
#define CDIM   256
#define NHEADS 8
#define HDIM   32
#define NWIN   64
#define BWIN   4096
#define MROWS  (BWIN * NTOK)      // 200704
#define QKVC   768
#define SCALE  0.17677669529663687f

__device__ __forceinline__ unsigned short f2bf(float f) {
    unsigned int u = __float_as_uint(f);
    u += 0x7fffu + ((u >> 16) & 1u);   // RNE
    return (unsigned short)(u >> 16);
}

__device__ __forceinline__ void load_lds16(const void* g, void* l) {
    __builtin_amdgcn_global_load_lds(
        (const __attribute__((address_space(1))) void*)g,
        (__attribute__((address_space(3))) void*)l, 16, 0, 0);
}

// ---------------------------------------------------------------------------
// Kernel 1: qkv = x @ qkv_w^T + qkv_b via bf16 MFMA, with FUSED fp32->bf16
// conversion of x (cvt_k eliminated). Both A (x, fp32) and B (weights, fp32)
// are reg-staged: global float4 loads -> f2bf pack -> swizzled ds_write_b128.
// Same swizzle involution as the (verified) ds_read side: slot ^= row&7.
// ---------------------------------------------------------------------------
__global__ __launch_bounds__(256) void qkv_gemm_mfma(
    const float* __restrict__ X, const float* __restrict__ W,
    const float* __restrict__ bias, bf16* __restrict__ qkv)
{
    __shared__ bf16 As[128 * 64];
    __shared__ bf16 Bs[128 * 64];
    const int tid = threadIdx.x;
    const int wid = tid >> 6;
    const int ln  = tid & 63;

    const int lin   = blockIdx.y * gridDim.x + blockIdx.x;
    const int chunk = (gridDim.x * gridDim.y) >> 3;
    const int swz   = (lin & 7) * chunk + (lin >> 3);
    const int rowBase = (swz / gridDim.x) * 128;
    const int colBase = (swz % gridDim.x) * 128;

    const int wr = wid >> 1, wc = wid & 1;

    f32x4 zero = {0.f, 0.f, 0.f, 0.f};
    f32x4 acc[4][4];
#pragma unroll
    for (int i = 0; i < 4; ++i)
#pragma unroll
        for (int j = 0; j < 4; ++j) acc[i][j] = zero;

    const int srow  = ln >> 3;        // row within 8-row chunk (0..7)
    const int gslot = ln & 7;         // 16B slot index within the row
    const int wslot = gslot ^ srow;   // swizzled LDS slot
    const size_t aRow0 = (size_t)(rowBase + wid * 32);
    const size_t bRow0 = (size_t)(colBase + wid * 32);

    for (int k0 = 0; k0 < CDIM; k0 += 64) {
        // ---- issue all global loads first (A: x fp32, B: weights fp32) ----
        float4 a0[4], a1[4], f0[4], f1[4];
#pragma unroll
        for (int c = 0; c < 4; ++c) {
            const float* gx = X + (aRow0 + c * 8 + srow) * CDIM + k0 + gslot * 8;
            a0[c] = *(const float4*)gx;
            a1[c] = *(const float4*)(gx + 4);
        }
#pragma unroll
        for (int c = 0; c < 4; ++c) {
            const float* gw = W + (size_t)(bRow0 + c * 8 + srow) * CDIM
                              + k0 + gslot * 8;
            f0[c] = *(const float4*)gw;
            f1[c] = *(const float4*)(gw + 4);
        }
        // ---- pack + swizzled LDS writes ----
#pragma unroll
        for (int c = 0; c < 4; ++c) {
            bf16x8 pk;
            pk[0] = (short)f2bf(a0[c].x); pk[1] = (short)f2bf(a0[c].y);
            pk[2] = (short)f2bf(a0[c].z); pk[3] = (short)f2bf(a0[c].w);
            pk[4] = (short)f2bf(a1[c].x); pk[5] = (short)f2bf(a1[c].y);
            pk[6] = (short)f2bf(a1[c].z); pk[7] = (short)f2bf(a1[c].w);
            *(bf16x8*)((char*)As + (wid * 32 + c * 8 + srow) * 128
                       + (wslot << 4)) = pk;
        }
#pragma unroll
        for (int c = 0; c < 4; ++c) {
            bf16x8 pk;
            pk[0] = (short)f2bf(f0[c].x); pk[1] = (short)f2bf(f0[c].y);
            pk[2] = (short)f2bf(f0[c].z); pk[3] = (short)f2bf(f0[c].w);
            pk[4] = (short)f2bf(f1[c].x); pk[5] = (short)f2bf(f1[c].y);
            pk[6] = (short)f2bf(f1[c].z); pk[7] = (short)f2bf(f1[c].w);
            *(bf16x8*)((char*)Bs + (wid * 32 + c * 8 + srow) * 128
                       + (wslot << 4)) = pk;
        }
        __syncthreads();
#pragma unroll
        for (int kk = 0; kk < 2; ++kk) {
            bf16x8 av[4], bv[4];
#pragma unroll
            for (int m = 0; m < 4; ++m) {
                int r = wr * 64 + m * 16 + (ln & 15);
                int g = kk * 4 + (ln >> 4);
                av[m] = *(const bf16x8*)((const char*)As +
                          (r * 128 + ((g ^ (r & 7)) << 4)));
            }
#pragma unroll
            for (int n = 0; n < 4; ++n) {
                int r = wc * 64 + n * 16 + (ln & 15);
                int g = kk * 4 + (ln >> 4);
                bv[n] = *(const bf16x8*)((const char*)Bs +
                          (r * 128 + ((g ^ (r & 7)) << 4)));
            }
#pragma unroll
            for (int m = 0; m < 4; ++m)
#pragma unroll
                for (int n = 0; n < 4; ++n)
                    acc[m][n] = __builtin_amdgcn_mfma_f32_16x16x32_bf16(
                        av[m], bv[n], acc[m][n], 0, 0, 0);
        }
        __syncthreads();
    }

    const int lq = ln >> 4;
    const int lr = ln & 15;
#pragma unroll
    for (int m = 0; m < 4; ++m) {
#pragma unroll
        for (int q = 0; q < 4; ++q) {
            int row = rowBase + wr * 64 + m * 16 + lq * 4 + q;
            int bw = row / NTOK;
            int nn = row - bw * NTOK;
            bf16* dst0 = qkv + (size_t)bw * 24 * (NTOK * HDIM) + nn * HDIM;
#pragma unroll
            for (int n = 0; n < 4; ++n) {
                int col = colBase + wc * 64 + n * 16 + lr;
                int which = col >> 8, hh = (col >> 5) & 7, dd = col & 31;
                float v = acc[m][n][q] + bias[col];
                dst0[(size_t)(which * 8 + hh) * (NTOK * HDIM) + dd] =
                    __float2bfloat16(v);
            }
        }
    }
}

// ---------------------------------------------------------------------------
// Kernel 2: MFMA attention. Same structure as R5 (verified passing), plus:
// mask window (9.6 KB, shared by all 8 heads) and bias table (5.4 KB, fp32)
// staged into LDS once per block -> all softmax gathers hit LDS instead of
// scattered VMEM. One __syncthreads after staging; waves independent after.
// ---------------------------------------------------------------------------
__global__ __launch_bounds__(256) void attn_mfma_k(
    const bf16* __restrict__ qkv, const float* __restrict__ mask,
    const float* __restrict__ bt, float* __restrict__ attn_out,
    bf16* __restrict__ o_ws)
{
    const int b  = blockIdx.x;
    const int wv = threadIdx.x >> 6;
    const int ln = threadIdx.x & 63;
    const int r  = ln & 15;     // fragment row/col lane
    const int g  = ln >> 4;     // k-group 0..3

    __shared__ short vt_all[4][32 * 64];   // Vt[d][j], swizzled, 4KB/wave
    __shared__ short ps_all[4][64 * 64];   // P[i][j],  swizzled, 8KB/wave
    __shared__ float mlds[NTOK * NTOK];    // mask window, 9604 B
    __shared__ float btlds[169 * NHEADS];  // bias table, 5408 B
    char* vt = (char*)vt_all[wv];
    char* ps = (char*)ps_all[wv];

    const float* mrow = mask + (size_t)(b & (NWIN - 1)) * (NTOK * NTOK);
    for (int e = threadIdx.x; e < NTOK * NTOK; e += 256) mlds[e] = mrow[e];
    for (int e = threadIdx.x; e < 169 * NHEADS; e += 256) btlds[e] = bt[e];
    __syncthreads();

#pragma unroll 1
    for (int hh = 0; hh < 2; ++hh) {
        const int h = wv + hh * 4;
        const bf16* qp = qkv + ((size_t)b * 24 + h)      * (NTOK * HDIM);
        const bf16* kp = qkv + ((size_t)b * 24 + 8 + h)  * (NTOK * HDIM);
        const bf16* vp = qkv + ((size_t)b * 24 + 16 + h) * (NTOK * HDIM);

        // ---- Q,K fragments direct from global (rows clamped to 48) ----
        bf16x8 qf[4], kf[4];
#pragma unroll
        for (int t = 0; t < 4; ++t) {
            int qi = t * 16 + r; if (qi > 48) qi = 48;
            qf[t] = *(const bf16x8*)(qp + qi * HDIM + g * 8);
            kf[t] = *(const bf16x8*)(kp + qi * HDIM + g * 8);
        }

        // ---- stage V transposed into LDS: Vt[d][j=ln], zero pad j>=49 ----
        bf16x8 vr0 = {0,0,0,0,0,0,0,0}, vr1 = vr0, vr2 = vr0, vr3 = vr0;
        if (ln < NTOK) {
            vr0 = *(const bf16x8*)(vp + ln * HDIM);
            vr1 = *(const bf16x8*)(vp + ln * HDIM + 8);
            vr2 = *(const bf16x8*)(vp + ln * HDIM + 16);
            vr3 = *(const bf16x8*)(vp + ln * HDIM + 24);
        }
#pragma unroll
        for (int d = 0; d < 32; ++d) {
            short val = (d < 8) ? vr0[d & 7] : (d < 16) ? vr1[d & 7]
                      : (d < 24) ? vr2[d & 7] : vr3[d & 7];
            *(short*)(vt + d * 128 + ((((ln >> 3)) ^ (d & 7)) << 4)
                      + (ln & 7) * 2) = val;
        }

        // ---- QK^T: S^T tile; s[mt][nt], m=j (K rows), n=i (Q rows) ----
        f32x4 zero = {0.f, 0.f, 0.f, 0.f};
        f32x4 s[4][4];
#pragma unroll
        for (int mt = 0; mt < 4; ++mt)
#pragma unroll
            for (int nt = 0; nt < 4; ++nt) s[mt][nt] = zero;
#pragma unroll
        for (int mt = 0; mt < 4; ++mt)
#pragma unroll
            for (int nt = 0; nt < 4; ++nt)
                s[mt][nt] = __builtin_amdgcn_mfma_f32_16x16x32_bf16(
                    kf[mt], qf[nt], s[mt][nt], 0, 0, 0);

        // ---- bias + mask + softmax (per nt: row i = nt*16+r) ----
        float* aout = attn_out + (((size_t)b * NHEADS + h) * NTOK) * NTOK;
#pragma unroll
        for (int nt = 0; nt < 4; ++nt) {
            const int i = nt * 16 + r;
            const bool iok = (i < NTOK);
            const int ih = (i * 9363) >> 16;
            const int iw = i - ih * 7;
            float sv[4][4];
#pragma unroll
            for (int mt = 0; mt < 4; ++mt)
#pragma unroll
                for (int q = 0; q < 4; ++q) {
                    const int j = mt * 16 + g * 4 + q;
                    float v = -1e30f;
                    if (iok && j < NTOK) {
                        const int jh = (j * 9363) >> 16;
                        const int jw = j - jh * 7;
                        float bias = btlds[((ih - jh + 6) * 13 +
                                            (iw - jw + 6)) * NHEADS + h];
                        v = s[mt][nt][q] * SCALE + bias + mlds[i * NTOK + j];
                    }
                    sv[mt][q] = v;
                }
            float mx = -1e30f;
#pragma unroll
            for (int mt = 0; mt < 4; ++mt)
#pragma unroll
                for (int q = 0; q < 4; ++q) mx = fmaxf(mx, sv[mt][q]);
            mx = fmaxf(mx, __shfl_xor(mx, 16));
            mx = fmaxf(mx, __shfl_xor(mx, 32));
            float sum = 0.f;
#pragma unroll
            for (int mt = 0; mt < 4; ++mt)
#pragma unroll
                for (int q = 0; q < 4; ++q) {
                    sv[mt][q] = __expf(sv[mt][q] - mx);
                    sum += sv[mt][q];
                }
            sum += __shfl_xor(sum, 16);
            sum += __shfl_xor(sum, 32);
            const float inv = 1.0f / sum;
            // write attn_out (fp32) + pack P bf16 into swizzled LDS
#pragma unroll
            for (int mt = 0; mt < 4; ++mt) {
#pragma unroll
                for (int qh = 0; qh < 2; ++qh) {
                    float p0 = sv[mt][qh * 2]     * inv;
                    float p1 = sv[mt][qh * 2 + 1] * inv;
                    const int j0 = mt * 16 + g * 4 + qh * 2;
                    if (iok) {
                        if (j0 < NTOK)     aout[(size_t)i * NTOK + j0]     = p0;
                        if (j0 + 1 < NTOK) aout[(size_t)i * NTOK + j0 + 1] = p1;
                    }
                    unsigned int pk = (unsigned int)f2bf(p0) |
                                      ((unsigned int)f2bf(p1) << 16);
                    *(unsigned int*)(ps + i * 128 +
                        (((2 * mt + (g >> 1)) ^ (r & 7)) << 4) +
                        (g & 1) * 8 + qh * 4) = pk;
                }
            }
        }

        // ---- PV: O[i][d] = sum_j P[i][j] V[j][d] ----
        f32x4 o[4][2];
#pragma unroll
        for (int mt = 0; mt < 4; ++mt)
#pragma unroll
            for (int nt = 0; nt < 2; ++nt) o[mt][nt] = zero;
#pragma unroll
        for (int ks = 0; ks < 2; ++ks) {
            bf16x8 pa[4], vb[2];
#pragma unroll
            for (int mt = 0; mt < 4; ++mt) {
                const int row = mt * 16 + r;
                pa[mt] = *(const bf16x8*)(ps + row * 128 +
                           (((ks * 4 + g) ^ (r & 7)) << 4));
            }
#pragma unroll
            for (int nt = 0; nt < 2; ++nt) {
                const int row = nt * 16 + r;
                vb[nt] = *(const bf16x8*)(vt + row * 128 +
                           (((ks * 4 + g) ^ (r & 7)) << 4));
            }
#pragma unroll
            for (int mt = 0; mt < 4; ++mt)
#pragma unroll
                for (int nt = 0; nt < 2; ++nt)
                    o[mt][nt] = __builtin_amdgcn_mfma_f32_16x16x32_bf16(
                        pa[mt], vb[nt], o[mt][nt], 0, 0, 0);
        }

        // ---- store O (bf16) into o_ws[b][i][h*32+d] ----
#pragma unroll
        for (int mt = 0; mt < 4; ++mt) {
#pragma unroll
            for (int q = 0; q < 4; ++q) {
                const int i = mt * 16 + g * 4 + q;
                if (i < NTOK) {
#pragma unroll
                    for (int nt = 0; nt < 2; ++nt) {
                        const int d = nt * 16 + r;
                        o_ws[((size_t)b * NTOK + i) * CDIM + h * HDIM + d] =
                            __float2bfloat16(o[mt][nt][q]);
                    }
                }
            }
        }
    }
}

// ---------------------------------------------------------------------------
// Kernel 3: out = O @ proj_w^T + proj_b via bf16 MFMA.  [UNCHANGED, passing]
// ---------------------------------------------------------------------------
__global__ __launch_bounds__(256) void proj_gemm_mfma(
    const bf16* __restrict__ A, const float* __restrict__ W,
    const float* __restrict__ bias, float* __restrict__ out)
{
    __shared__ bf16 As[128 * 64];
    __shared__ bf16 Bs[128 * 64];
    const int tid = threadIdx.x;
    const int wid = tid >> 6;
    const int ln  = tid & 63;

    const int lin   = blockIdx.y * gridDim.x + blockIdx.x;
    const int chunk = (gridDim.x * gridDim.y) >> 3;
    const int swz   = (lin & 7) * chunk + (lin >> 3);
    const int rowBase = (swz / gridDim.x) * 128;
    const int colBase = (swz % gridDim.x) * 128;

    const int wr = wid >> 1, wc = wid & 1;

    f32x4 zero = {0.f, 0.f, 0.f, 0.f};
    f32x4 acc[4][4];
#pragma unroll
    for (int i = 0; i < 4; ++i)
#pragma unroll
        for (int j = 0; j < 4; ++j) acc[i][j] = zero;

    const int srow  = ln >> 3;
    const int gslot = ln & 7;
    const int sslotA = gslot ^ srow;
    const int swslotB = gslot ^ srow;
    const size_t aRow0 = (size_t)(rowBase + wid * 32);
    const size_t bRow0 = (size_t)(colBase + wid * 32);

    for (int k0 = 0; k0 < CDIM; k0 += 64) {
#pragma unroll
        for (int c = 0; c < 4; ++c) {
            const bf16* ga = A + (aRow0 + c * 8 + srow) * CDIM + k0 + sslotA * 8;
            load_lds16(ga, &As[(wid * 32 + c * 8) * 64]);
        }
        float4 f0[4], f1[4];
#pragma unroll
        for (int c = 0; c < 4; ++c) {
            const float* gw = W + (size_t)(bRow0 + c * 8 + srow) * CDIM
                              + k0 + gslot * 8;
            f0[c] = *(const float4*)gw;
            f1[c] = *(const float4*)(gw + 4);
        }
#pragma unroll
        for (int c = 0; c < 4; ++c) {
            bf16x8 pk;
            pk[0] = (short)f2bf(f0[c].x); pk[1] = (short)f2bf(f0[c].y);
            pk[2] = (short)f2bf(f0[c].z); pk[3] = (short)f2bf(f0[c].w);
            pk[4] = (short)f2bf(f1[c].x); pk[5] = (short)f2bf(f1[c].y);
            pk[6] = (short)f2bf(f1[c].z); pk[7] = (short)f2bf(f1[c].w);
            *(bf16x8*)((char*)Bs + (wid * 32 + c * 8 + srow) * 128
                       + (swslotB << 4)) = pk;
        }
        __syncthreads();
#pragma unroll
        for (int kk = 0; kk < 2; ++kk) {
            bf16x8 av[4], bv[4];
#pragma unroll
            for (int m = 0; m < 4; ++m) {
                int r = wr * 64 + m * 16 + (ln & 15);
                int g = kk * 4 + (ln >> 4);
                av[m] = *(const bf16x8*)((const char*)As +
                          (r * 128 + ((g ^ (r & 7)) << 4)));
            }
#pragma unroll
            for (int n = 0; n < 4; ++n) {
                int r = wc * 64 + n * 16 + (ln & 15);
                int g = kk * 4 + (ln >> 4);
                bv[n] = *(const bf16x8*)((const char*)Bs +
                          (r * 128 + ((g ^ (r & 7)) << 4)));
            }
#pragma unroll
            for (int m = 0; m < 4; ++m)
#pragma unroll
                for (int n = 0; n < 4; ++n)
                    acc[m][n] = __builtin_amdgcn_mfma_f32_16x16x32_bf16(
                        av[m], bv[n], acc[m][n], 0, 0, 0);
        }
        __syncthreads();
    }

    const int lq = ln >> 4;
    const int lr = ln & 15;
#pragma unroll
    for (int m = 0; m < 4; ++m) {
#pragma unroll
        for (int q = 0; q < 4; ++q) {
            int row = rowBase + wr * 64 + m * 16 + lq * 4 + q;
            float* orow = out + (size_t)row * CDIM;
#pragma unroll
            for (int n = 0; n < 4; ++n) {
                int col = colBase + wc * 64 + n * 16 + lr;
                orow[col] = acc[m][n][q] + bias[col];
            }
        }
    }
}

// ---------------------------------------------------------------------------
extern "C" void kernel_launch(void* const* d_in, const int* in_sizes, int n_in,
                              void* d_out, int out_size, void* d_ws, size_t ws_size,
                              hipStream_t stream)
{
    const float* x      = (const float*)d_in[0];   // [4096,49,256]
    const float* mask   = (const float*)d_in[1];   // [64,49,49]
    const float* qkv_w  = (const float*)d_in[2];   // [768,256]
    const float* qkv_b  = (const float*)d_in[3];   // [768]
    const float* proj_w = (const float*)d_in[4];   // [256,256]
    const float* proj_b = (const float*)d_in[5];   // [256]
    const float* bt     = (const float*)d_in[6];   // [169,8]

    float* out      = (float*)d_out;                       // [4096,49,256]
    float* attn_out = out + (size_t)MROWS * CDIM;          // [4096,8,49,49]

    bf16* qkv_ws = (bf16*)d_ws;                            // [MROWS*768] bf16
    bf16* o_ws   = qkv_ws + (size_t)MROWS * QKVC;          // [MROWS*256] bf16
    // total ws footprint: MROWS*(768+256)*2 B = 411,041,792 B (unchanged)

    // Kernel 1: QKV projection with fused x fp32->bf16 (cvt_k eliminated)
    qkv_gemm_mfma<<<dim3(QKVC/128, MROWS/128), 256, 0, stream>>>(
        x, qkv_w, qkv_b, qkv_ws);

    // Kernel 2: attention per window (all 8 heads), LDS-staged mask/bias
    attn_mfma_k<<<dim3(BWIN), 256, 0, stream>>>(qkv_ws, mask, bt,
                                                attn_out, o_ws);

    // Kernel 3: output projection via MFMA
    proj_gemm_mfma<<<dim3(CDIM/128, MROWS/128), 256, 0, stream>>>(
        o_ws, proj_w, proj_b, out);
}